// Round 10
// baseline (337.082 us; speedup 1.0000x reference)
//
#include <hip/hip_runtime.h>
#include <hip/hip_bf16.h>

#define N_NODES 40000
#define N_EDGES 640000
#define E_TOT   (N_EDGES + N_NODES)
#define NUM_GRAPHS 64
#define SCAN_BLOCKS 160
#define SCAN_CHUNK  250   // 160*250 = 40000

// setup kernel partition
#define CVTX_BLOCKS 5000              // N*128/4 float4s / 256
#define CVTW_BLOCKS 144               // 36864 / 256
#define ZERO_INTS   (N_NODES + NUM_GRAPHS * 32 + NUM_GRAPHS)   // 42112
#define ZERO_BLOCKS ((ZERO_INTS + 255) / 256)                  // 165

typedef __attribute__((ext_vector_type(8))) short bf16x8;
typedef __attribute__((ext_vector_type(4))) float f32x4;

__device__ inline float bf2f(unsigned short u) {
    union { unsigned int i; float f; } v; v.i = ((unsigned int)u) << 16; return v.f;
}
__device__ inline unsigned short f2bf(float f) {
    union { float f; unsigned int i; } v; v.f = f;
    unsigned int r = v.i + 0x7FFF + ((v.i >> 16) & 1);
    return (unsigned short)(r >> 16);
}

// ---------------- fused setup: x->bf16, W transposes, zero counts/gsum/gcnt ----------------

__global__ __launch_bounds__(256) void setup_kernel(const float* __restrict__ x,
                                                    const float* __restrict__ W0,
                                                    const float* __restrict__ W1,
                                                    const float* __restrict__ W2,
                                                    unsigned short* __restrict__ Xb,
                                                    unsigned short* __restrict__ Wt0,
                                                    unsigned short* __restrict__ Wt1,
                                                    unsigned short* __restrict__ Wt2,
                                                    int* __restrict__ zbase) {
    int b = blockIdx.x;
    int tid = threadIdx.x;
    if (b < CVTX_BLOCKS) {
        int i = b * 256 + tid;
        float4 v = ((const float4*)x)[i];
        ushort4 o;
        o.x = f2bf(v.x); o.y = f2bf(v.y); o.z = f2bf(v.z); o.w = f2bf(v.w);
        ((ushort4*)Xb)[i] = o;
    } else if (b < CVTX_BLOCKS + CVTW_BLOCKS) {
        int idx = (b - CVTX_BLOCKS) * 256 + tid;
        if (idx < 16384) {
            int n = idx >> 7, k = idx & 127;
            Wt0[idx] = f2bf(W0[k * 128 + n]);
        } else if (idx < 32768) {
            int i = idx - 16384;
            int n = i >> 7, k = i & 127;
            Wt1[i] = f2bf(W1[k * 128 + n]);
        } else {
            int i = idx - 32768;
            int n = i >> 7, k = i & 127;   // n in [0,32)
            Wt2[i] = f2bf(W2[k * 32 + n]);
        }
    } else {
        int i = (b - CVTX_BLOCKS - CVTW_BLOCKS) * 256 + tid;
        if (i < ZERO_INTS) zbase[i] = 0;
    }
}

// ---------------- CSR build ----------------

__global__ __launch_bounds__(256) void hist_rank_kernel(const int* __restrict__ edst,
                                                        int* __restrict__ counts,
                                                        int* __restrict__ rank) {
    int e = blockIdx.x * 256 + threadIdx.x;
    if (e >= E_TOT) return;
    int d = (e < N_EDGES) ? edst[e] : (e - N_EDGES);
    rank[e] = atomicAdd(&counts[d], 1);
}

__global__ __launch_bounds__(256) void bsum_kernel(const int* __restrict__ counts,
                                                   int* __restrict__ bsum) {
    __shared__ int ws[4];
    int b = blockIdx.x, tid = threadIdx.x;
    int idx = b * SCAN_CHUNK + tid;
    int v = (tid < SCAN_CHUNK) ? counts[idx] : 0;
#pragma unroll
    for (int off = 32; off >= 1; off >>= 1) v += __shfl_down(v, off, 64);
    if ((tid & 63) == 0) ws[tid >> 6] = v;
    __syncthreads();
    if (tid == 0) bsum[b] = ws[0] + ws[1] + ws[2] + ws[3];
}

__global__ __launch_bounds__(256) void bscan_kernel(const int* __restrict__ bsum,
                                                    int* __restrict__ bofs) {
    __shared__ int s[256];
    int tid = threadIdx.x;
    int v = (tid < SCAN_BLOCKS) ? bsum[tid] : 0;
    s[tid] = v;
    __syncthreads();
    for (int off = 1; off < 256; off <<= 1) {
        int t = (tid >= off) ? s[tid - off] : 0;
        __syncthreads();
        s[tid] += t;
        __syncthreads();
    }
    if (tid < SCAN_BLOCKS) bofs[tid] = s[tid] - v;  // exclusive
}

__global__ __launch_bounds__(256) void boffs_kernel(const int* __restrict__ counts,
                                                    const int* __restrict__ bofs,
                                                    int* __restrict__ offs) {
    __shared__ int s[256];
    int b = blockIdx.x, tid = threadIdx.x;
    int idx = b * SCAN_CHUNK + tid;
    int v = (tid < SCAN_CHUNK) ? counts[idx] : 0;
    s[tid] = v;
    __syncthreads();
    for (int off = 1; off < 256; off <<= 1) {
        int t = (tid >= off) ? s[tid - off] : 0;
        __syncthreads();
        s[tid] += t;
        __syncthreads();
    }
    int incl = s[tid];
    int base = bofs[b];
    if (tid < SCAN_CHUNK) {
        offs[idx] = base + incl - v;
        if (idx == N_NODES - 1) offs[N_NODES] = base + incl;
    }
}

__global__ __launch_bounds__(256) void scatter_kernel(const int* __restrict__ esrc,
                                                      const int* __restrict__ edst,
                                                      const int* __restrict__ offs,
                                                      const int* __restrict__ rank,
                                                      int* __restrict__ ssrc) {
    int e = blockIdx.x * 256 + threadIdx.x;
    if (e >= E_TOT) return;
    int d, s;
    if (e < N_EDGES) { d = edst[e]; s = esrc[e]; }
    else             { d = e - N_EDGES; s = d; }
    ssrc[offs[d] + rank[e]] = s;
}

// ---------------- MFMA GEMM + attention scores (128 -> 128) ----------------
__global__ __launch_bounds__(256) void gemm128_mfma(const unsigned short* __restrict__ Xb,
                                                    const unsigned short* __restrict__ Wt,
                                                    const float* __restrict__ asrc,
                                                    const float* __restrict__ adst,
                                                    unsigned short* __restrict__ Hb,
                                                    float* __restrict__ ALS_t,
                                                    float* __restrict__ ALD_t) {
    int wave = threadIdx.x >> 6;
    int lane = threadIdx.x & 63;
    int l15 = lane & 15;
    int q = lane >> 4;
    int r0 = (blockIdx.x * 4 + wave) * 16;   // 625*4*16 = 40000 exact

    f32x4 acc[8];
#pragma unroll
    for (int t = 0; t < 8; ++t) acc[t] = (f32x4){0.f, 0.f, 0.f, 0.f};

    float asv[8], adv[8];
#pragma unroll
    for (int t = 0; t < 8; ++t) {
        int c = t * 16 + l15;
        asv[t] = asrc[c];
        adv[t] = adst[c];
    }

    const unsigned short* xrow = Xb + (long)(r0 + l15) * 128 + q * 8;
    const unsigned short* wrow = Wt + (long)l15 * 128 + q * 8;
#pragma unroll
    for (int kt = 0; kt < 4; ++kt) {
        bf16x8 a = *(const bf16x8*)(xrow + kt * 32);
#pragma unroll
        for (int t = 0; t < 8; ++t) {
            bf16x8 b = *(const bf16x8*)(wrow + (long)t * 16 * 128 + kt * 32);
            acc[t] = __builtin_amdgcn_mfma_f32_16x16x32_bf16(a, b, acc[t], 0, 0, 0);
        }
    }

#pragma unroll
    for (int t = 0; t < 8; ++t)
#pragma unroll
        for (int i = 0; i < 4; ++i)
            Hb[(long)(r0 + q * 4 + i) * 128 + t * 16 + l15] = f2bf(acc[t][i]);

#pragma unroll
    for (int i = 0; i < 4; ++i) {
        float ps0 = acc[0][i] * asv[0] + acc[1][i] * asv[1];
        float ps1 = acc[2][i] * asv[2] + acc[3][i] * asv[3];
        float ps2 = acc[4][i] * asv[4] + acc[5][i] * asv[5];
        float ps3 = acc[6][i] * asv[6] + acc[7][i] * asv[7];
        float pd0 = acc[0][i] * adv[0] + acc[1][i] * adv[1];
        float pd1 = acc[2][i] * adv[2] + acc[3][i] * adv[3];
        float pd2 = acc[4][i] * adv[4] + acc[5][i] * adv[5];
        float pd3 = acc[6][i] * adv[6] + acc[7][i] * adv[7];
#pragma unroll
        for (int m = 1; m < 16; m <<= 1) {
            ps0 += __shfl_xor(ps0, m, 16); ps1 += __shfl_xor(ps1, m, 16);
            ps2 += __shfl_xor(ps2, m, 16); ps3 += __shfl_xor(ps3, m, 16);
            pd0 += __shfl_xor(pd0, m, 16); pd1 += __shfl_xor(pd1, m, 16);
            pd2 += __shfl_xor(pd2, m, 16); pd3 += __shfl_xor(pd3, m, 16);
        }
        int r = r0 + q * 4 + i;
        if (l15 < 4) {
            float v = (l15 == 0) ? ps0 : (l15 == 1) ? ps1 : (l15 == 2) ? ps2 : ps3;
            ALS_t[l15 * N_NODES + r] = v;
        } else if (l15 < 8) {
            int h = l15 - 4;
            float v = (h == 0) ? pd0 : (h == 1) ? pd1 : (h == 2) ? pd2 : pd3;
            ALD_t[h * N_NODES + r] = v;
        }
    }
}

// ---------------- MFMA GEMM (128 -> 32, 1 head) ----------------
__global__ __launch_bounds__(256) void gemm32_mfma(const unsigned short* __restrict__ Xb,
                                                   const unsigned short* __restrict__ Wt2,
                                                   const float* __restrict__ asrc,
                                                   const float* __restrict__ adst,
                                                   unsigned short* __restrict__ H2b,
                                                   float* __restrict__ ALS,
                                                   float* __restrict__ ALD) {
    int wave = threadIdx.x >> 6;
    int lane = threadIdx.x & 63;
    int l15 = lane & 15;
    int q = lane >> 4;
    int r0 = (blockIdx.x * 4 + wave) * 16;   // 625*4*16 = 40000 exact

    f32x4 acc[2];
    acc[0] = (f32x4){0.f, 0.f, 0.f, 0.f};
    acc[1] = (f32x4){0.f, 0.f, 0.f, 0.f};

    const unsigned short* xrow = Xb + (long)(r0 + l15) * 128 + q * 8;
    const unsigned short* wrow = Wt2 + (long)l15 * 128 + q * 8;
#pragma unroll
    for (int kt = 0; kt < 4; ++kt) {
        bf16x8 a = *(const bf16x8*)(xrow + kt * 32);
#pragma unroll
        for (int t = 0; t < 2; ++t) {
            bf16x8 b = *(const bf16x8*)(wrow + (long)t * 16 * 128 + kt * 32);
            acc[t] = __builtin_amdgcn_mfma_f32_16x16x32_bf16(a, b, acc[t], 0, 0, 0);
        }
    }

    float as0 = asrc[l15], as1 = asrc[16 + l15];
    float ad0 = adst[l15], ad1 = adst[16 + l15];
#pragma unroll
    for (int t = 0; t < 2; ++t)
#pragma unroll
        for (int i = 0; i < 4; ++i)
            H2b[(long)(r0 + q * 4 + i) * 32 + t * 16 + l15] = f2bf(acc[t][i]);

#pragma unroll
    for (int i = 0; i < 4; ++i) {
        float ps = acc[0][i] * as0 + acc[1][i] * as1;
        float pd = acc[0][i] * ad0 + acc[1][i] * ad1;
#pragma unroll
        for (int m = 1; m < 16; m <<= 1) {
            ps += __shfl_xor(ps, m, 16);
            pd += __shfl_xor(pd, m, 16);
        }
        if (l15 == 0) {
            int r = r0 + q * 4 + i;
            ALS[r] = ps;
            ALD[r] = pd;
        }
    }
}

// ---------------- Edge aggregation: software-pipelined 2-chunk gather ----------------
// One wave per node. Chunk = 16 edges. Issue order: A.meta, B.meta, A.gather(16),
// B.gather(16), consume A, consume B -> up to 32 H-row gathers in flight (vmcnt
// is in-order, so consuming A leaves B outstanding). Only hvA/hvB arrays stay
// live (st/wt via transient shuffles) to keep VGPR ~55 -> 8 waves/SIMD.
__global__ __launch_bounds__(256) void agg128(const unsigned short* __restrict__ Hb,
                                              const float* __restrict__ ALS_t,
                                              const float* __restrict__ ALD_t,
                                              const int* __restrict__ offs,
                                              const int* __restrict__ ssrc,
                                              const float* __restrict__ bias,
                                              unsigned short* __restrict__ OUTb) {
    int n = blockIdx.x * 4 + (threadIdx.x >> 6);
    n = __builtin_amdgcn_readfirstlane(n);
    if (n >= N_NODES) return;
    int lane = threadIdx.x & 63;
    int c = lane * 2;
    int head = lane >> 4;
    int e16 = lane & 15;
    float aldh = ALD_t[head * N_NODES + n];
    const float* alsh = ALS_t + (long)head * N_NODES;
    int j0 = __builtin_amdgcn_readfirstlane(offs[n]);
    int j1 = __builtin_amdgcn_readfirstlane(offs[n + 1]);
    float a0 = 0.f, a1 = 0.f, dsum = 0.f;

    int jb = j0;
    // prologue: chunk A meta
    int sA; float wA;
    {
        int j = jb + e16;
        int jc = (j < j1) ? j : (j1 - 1);
        sA = ssrc[jc];
        float e = alsh[sA] + aldh;
        e = (e > 0.f) ? e : 0.2f * e;
        wA = (j < j1) ? __expf(e) : 0.f;
    }
    while (true) {
        int jbB = jb + 16;
        bool hasB = (jbB < j1);   // wave-uniform
        int sB = 0; float wB = 0.f;
        if (hasB) {
            int j = jbB + e16;
            int jc = (j < j1) ? j : (j1 - 1);
            sB = ssrc[jc];
            float e = alsh[sB] + aldh;
            e = (e > 0.f) ? e : 0.2f * e;
            wB = (j < j1) ? __expf(e) : 0.f;
        }
        unsigned int hvA[16];
#pragma unroll
        for (int t = 0; t < 16; ++t) {
            int st = __shfl(sA, t, 16);
            hvA[t] = *(const unsigned int*)(Hb + (long)st * 128 + c);
        }
        if (hasB) {
            unsigned int hvB[16];
#pragma unroll
            for (int t = 0; t < 16; ++t) {
                int st = __shfl(sB, t, 16);
                hvB[t] = *(const unsigned int*)(Hb + (long)st * 128 + c);
            }
#pragma unroll
            for (int t = 0; t < 16; ++t) {
                float wt = __shfl(wA, t, 16);
                dsum += wt;
                a0 += wt * bf2f((unsigned short)(hvA[t] & 0xFFFF));
                a1 += wt * bf2f((unsigned short)(hvA[t] >> 16));
            }
#pragma unroll
            for (int t = 0; t < 16; ++t) {
                float wt = __shfl(wB, t, 16);
                dsum += wt;
                a0 += wt * bf2f((unsigned short)(hvB[t] & 0xFFFF));
                a1 += wt * bf2f((unsigned short)(hvB[t] >> 16));
            }
        } else {
#pragma unroll
            for (int t = 0; t < 16; ++t) {
                float wt = __shfl(wA, t, 16);
                dsum += wt;
                a0 += wt * bf2f((unsigned short)(hvA[t] & 0xFFFF));
                a1 += wt * bf2f((unsigned short)(hvA[t] >> 16));
            }
        }
        jb += 32;
        if (jb >= j1) break;
        int j = jb + e16;
        int jc = (j < j1) ? j : (j1 - 1);
        sA = ssrc[jc];
        float e = alsh[sA] + aldh;
        e = (e > 0.f) ? e : 0.2f * e;
        wA = (j < j1) ? __expf(e) : 0.f;
    }
    float inv = 1.0f / dsum;
    float o0 = a0 * inv + bias[c];
    float o1 = a1 * inv + bias[c + 1];
    o0 = (o0 > 0.f) ? o0 : (__expf(o0) - 1.f);
    o1 = (o1 > 0.f) ? o1 : (__expf(o1) - 1.f);
    ushort2 ob; ob.x = f2bf(o0); ob.y = f2bf(o1);
    *(ushort2*)(OUTb + (long)n * 128 + c) = ob;
}

// 32-channel, 1-head: one wave per node (upper 32 lanes duplicate channel work;
// same 64B line, no extra traffic), same 2-chunk pipeline, uniform control flow.
__global__ __launch_bounds__(256) void agg32(const unsigned short* __restrict__ H2b,
                                             const float* __restrict__ ALS,
                                             const float* __restrict__ ALD,
                                             const int* __restrict__ offs,
                                             const int* __restrict__ ssrc,
                                             const float* __restrict__ bias,
                                             float* __restrict__ OUT) {
    int n = blockIdx.x * 4 + (threadIdx.x >> 6);
    n = __builtin_amdgcn_readfirstlane(n);
    if (n >= N_NODES) return;
    int lane = threadIdx.x & 63;
    int col = lane & 31;
    int e16 = lane & 15;
    float aldn = ALD[n];
    int j0 = __builtin_amdgcn_readfirstlane(offs[n]);
    int j1 = __builtin_amdgcn_readfirstlane(offs[n + 1]);
    float a = 0.f, dsum = 0.f;

    int jb = j0;
    int sA; float wA;
    {
        int j = jb + e16;
        int jc = (j < j1) ? j : (j1 - 1);
        sA = ssrc[jc];
        float e = ALS[sA] + aldn;
        e = (e > 0.f) ? e : 0.2f * e;
        wA = (j < j1) ? __expf(e) : 0.f;
    }
    while (true) {
        int jbB = jb + 16;
        bool hasB = (jbB < j1);
        int sB = 0; float wB = 0.f;
        if (hasB) {
            int j = jbB + e16;
            int jc = (j < j1) ? j : (j1 - 1);
            sB = ssrc[jc];
            float e = ALS[sB] + aldn;
            e = (e > 0.f) ? e : 0.2f * e;
            wB = (j < j1) ? __expf(e) : 0.f;
        }
        unsigned short hvA[16];
#pragma unroll
        for (int t = 0; t < 16; ++t) {
            int st = __shfl(sA, t, 16);
            hvA[t] = H2b[st * 32 + col];
        }
        if (hasB) {
            unsigned short hvB[16];
#pragma unroll
            for (int t = 0; t < 16; ++t) {
                int st = __shfl(sB, t, 16);
                hvB[t] = H2b[st * 32 + col];
            }
#pragma unroll
            for (int t = 0; t < 16; ++t) {
                float wt = __shfl(wA, t, 16);
                dsum += wt;
                a += wt * bf2f(hvA[t]);
            }
#pragma unroll
            for (int t = 0; t < 16; ++t) {
                float wt = __shfl(wB, t, 16);
                dsum += wt;
                a += wt * bf2f(hvB[t]);
            }
        } else {
#pragma unroll
            for (int t = 0; t < 16; ++t) {
                float wt = __shfl(wA, t, 16);
                dsum += wt;
                a += wt * bf2f(hvA[t]);
            }
        }
        jb += 32;
        if (jb >= j1) break;
        int j = jb + e16;
        int jc = (j < j1) ? j : (j1 - 1);
        sA = ssrc[jc];
        float e = ALS[sA] + aldn;
        e = (e > 0.f) ? e : 0.2f * e;
        wA = (j < j1) ? __expf(e) : 0.f;
    }
    float o = a / dsum + bias[col];
    o = (o > 0.f) ? o : (__expf(o) - 1.f);
    if (lane < 32) OUT[n * 32 + col] = o;
}

// ---------------- Pooling + MLP ----------------
__global__ __launch_bounds__(256) void pool_kernel(const float* __restrict__ H3,
                                                   const int* __restrict__ batch,
                                                   float* __restrict__ gsum,
                                                   float* __restrict__ gcnt) {
    const int CHUNK = 40;
    int gid = (blockIdx.x * 256 + threadIdx.x) >> 5;
    int c = threadIdx.x & 31;
    int n0 = gid * CHUNK;
    if (n0 >= N_NODES) return;
    int n1 = n0 + CHUNK;
    if (n1 > N_NODES) n1 = N_NODES;
    int cur = batch[n0];
    float acc = 0.f;
    int cnt = 0;
    for (int n = n0; n < n1; ++n) {
        int b = batch[n];
        if (b != cur) {
            atomicAdd(&gsum[cur * 32 + c], acc);
            if (c == 0) atomicAdd(&gcnt[cur], (float)cnt);
            cur = b; acc = 0.f; cnt = 0;
        }
        acc += H3[n * 32 + c];
        cnt++;
    }
    atomicAdd(&gsum[cur * 32 + c], acc);
    if (c == 0) atomicAdd(&gcnt[cur], (float)cnt);
}

__global__ __launch_bounds__(256) void mlp_kernel(const float* __restrict__ gsum,
                                                  const float* __restrict__ gcnt,
                                                  const float* __restrict__ l1w,
                                                  const float* __restrict__ l1b,
                                                  const float* __restrict__ l2w,
                                                  const float* __restrict__ l2b,
                                                  float* __restrict__ out) {
    __shared__ float g[NUM_GRAPHS * 32];
    __shared__ float t1[NUM_GRAPHS * 128];
    int tid = threadIdx.x;
    for (int i = tid; i < NUM_GRAPHS * 32; i += 256) {
        float c = gcnt[i >> 5];
        g[i] = gsum[i] / fmaxf(c, 1.0f);
    }
    __syncthreads();
    for (int i = tid; i < NUM_GRAPHS * 128; i += 256) {
        int r = i >> 7, j = i & 127;
        float a = l1b[j];
        for (int k = 0; k < 32; ++k) a += g[r * 32 + k] * l1w[k * 128 + j];
        t1[i] = fmaxf(a, 0.f);
    }
    __syncthreads();
    for (int i = tid; i < NUM_GRAPHS * 8; i += 256) {
        int r = i >> 3, j = i & 7;
        float a = l2b[j];
        for (int k = 0; k < 128; ++k) a += t1[r * 128 + k] * l2w[k * 8 + j];
        out[i] = a;
    }
}

// ---------------- host ----------------

extern "C" void kernel_launch(void* const* d_in, const int* in_sizes, int n_in,
                              void* d_out, int out_size, void* d_ws, size_t ws_size,
                              hipStream_t stream) {
    const float* x      = (const float*)d_in[0];
    const int*   eidx   = (const int*)d_in[1];
    const int*   batch  = (const int*)d_in[2];
    const float* W0     = (const float*)d_in[3];
    const float* asrc0  = (const float*)d_in[4];
    const float* adst0  = (const float*)d_in[5];
    const float* b0     = (const float*)d_in[6];
    const float* W1     = (const float*)d_in[7];
    const float* asrc1  = (const float*)d_in[8];
    const float* adst1  = (const float*)d_in[9];
    const float* b1     = (const float*)d_in[10];
    const float* W2     = (const float*)d_in[11];
    const float* asrc2  = (const float*)d_in[12];
    const float* adst2  = (const float*)d_in[13];
    const float* b2     = (const float*)d_in[14];
    const float* l1w    = (const float*)d_in[15];
    const float* l1b    = (const float*)d_in[16];
    const float* l2w    = (const float*)d_in[17];
    const float* l2b    = (const float*)d_in[18];
    float* out = (float*)d_out;

    const int* esrc = eidx;
    const int* edst = eidx + N_EDGES;

    // workspace layout
    float* ALS  = (float*)d_ws;                       // N*4 (transposed [4][N]; layer2 uses [N])
    float* ALD  = ALS + N_NODES * 4;                  // N*4
    float* h3   = ALD + N_NODES * 4;                  // N*32
    int* counts = (int*)(h3 + (long)N_NODES * 32);    // N      <- zero from here
    float* gsum = (float*)(counts + N_NODES);         // 64*32
    float* gcnt = gsum + NUM_GRAPHS * 32;             // 64     <- zero to here
    int* offs   = (int*)(gcnt + NUM_GRAPHS);          // N+1
    int* bsum   = offs + (N_NODES + 1);               // SCAN_BLOCKS
    int* bofs   = bsum + SCAN_BLOCKS;                 // SCAN_BLOCKS
    int* rank   = bofs + SCAN_BLOCKS;                 // E_TOT
    int* ssrc   = rank + E_TOT;                       // E_TOT
    uintptr_t p = (uintptr_t)(ssrc + E_TOT);
    p = (p + 15) & ~(uintptr_t)15;
    unsigned short* Xb   = (unsigned short*)p;              // N*128 bf16
    unsigned short* Hb   = Xb + (long)N_NODES * 128;        // N*128 bf16
    unsigned short* OUTb = Hb + (long)N_NODES * 128;        // N*128 bf16
    unsigned short* H2b  = OUTb + (long)N_NODES * 128;      // N*32 bf16
    unsigned short* Wt0  = H2b + (long)N_NODES * 32;        // 128*128 bf16
    unsigned short* Wt1  = Wt0 + 128 * 128;                 // 128*128 bf16
    unsigned short* Wt2  = Wt1 + 128 * 128;                 // 32*128 bf16

    // fused setup: cvt_x + cvt_w + zero(counts/gsum/gcnt)
    setup_kernel<<<CVTX_BLOCKS + CVTW_BLOCKS + ZERO_BLOCKS, 256, 0, stream>>>(
        x, W0, W1, W2, Xb, Wt0, Wt1, Wt2, counts);

    // CSR build
    int eblocks = (E_TOT + 255) / 256;
    hist_rank_kernel<<<eblocks, 256, 0, stream>>>(edst, counts, rank);
    bsum_kernel<<<SCAN_BLOCKS, 256, 0, stream>>>(counts, bsum);
    bscan_kernel<<<1, 256, 0, stream>>>(bsum, bofs);
    boffs_kernel<<<SCAN_BLOCKS, 256, 0, stream>>>(counts, bofs, offs);
    scatter_kernel<<<eblocks, 256, 0, stream>>>(esrc, edst, offs, rank, ssrc);

    // layer 0
    gemm128_mfma<<<625, 256, 0, stream>>>(Xb, Wt0, asrc0, adst0, Hb, ALS, ALD);
    agg128<<<10000, 256, 0, stream>>>(Hb, ALS, ALD, offs, ssrc, b0, OUTb);

    // layer 1
    gemm128_mfma<<<625, 256, 0, stream>>>(OUTb, Wt1, asrc1, adst1, Hb, ALS, ALD);
    agg128<<<10000, 256, 0, stream>>>(Hb, ALS, ALD, offs, ssrc, b1, OUTb);

    // layer 2
    gemm32_mfma<<<625, 256, 0, stream>>>(OUTb, Wt2, asrc2, adst2, H2b, ALS, ALD);
    agg32<<<10000, 256, 0, stream>>>(H2b, ALS, ALD, offs, ssrc, b2, h3);

    // pool + MLP
    pool_kernel<<<125, 256, 0, stream>>>(h3, batch, gsum, gcnt);
    mlp_kernel<<<1, 256, 0, stream>>>(gsum, gcnt, l1w, l1b, l2w, l2b, out);
}